// Round 8
// baseline (112.713 us; speedup 1.0000x reference)
//
#include <hip/hip_runtime.h>

#define L_ 8
#define B_ 16
#define D_ 1024
#define JT 32              // output-column tile per block
#define IG 8               // i-groups per block (tid >> 5)
#define ILEN (D_ / IG)     // 128 reduction rows per i-group
#define PF 64              // W rows prefetched before/through the h stage

// One block computes out[b, jt*JT : (jt+1)*JT] with the FULL i-reduction.
// Grid: B_ * (D_/JT) = 512 blocks, 256 threads (2 blocks/CU).
__global__ __launch_bounds__(256) void layer_full(
    const float* __restrict__ h,     // [B][D] input activations
    const float* __restrict__ W,     // layer base [B][D][D]
    const float* __restrict__ bias,  // layer base [B][D]
    const int*   __restrict__ mask,  // layer base [B][D]
    float* __restrict__ hout)        // [B][D]
{
    const int blk = blockIdx.x;
    const int b   = blk / (D_ / JT);
    const int jt  = blk % (D_ / JT);
    const int tid = threadIdx.x;
    const int jl  = tid & 31;        // lane within j-tile
    const int ig  = tid >> 5;        // i-group 0..7

    // 1) Dependent h load first (heads the vmcnt queue).
    const float4 hv4 = ((const float4*)(h + (size_t)b * D_))[tid];

    // 2) Tiny epilogue loads next (needed last, issued early).
    float bsv = 0.f;
    int   mv  = 0;
    const int t = b * D_ + jt * JT + (tid & 31);
    if (tid < JT) { bsv = bias[t]; mv = mask[t]; }

    // 3) 64-row W prefetch — stays in flight through the h stage + barrier.
    const float* __restrict__ Wp =
        W + (size_t)b * D_ * D_ + (size_t)(ig * ILEN) * D_ + jt * JT + jl;
    float pf[PF];
#pragma unroll
    for (int p = 0; p < PF; ++p)
        pf[p] = __builtin_nontemporal_load(&Wp[(size_t)p * D_]);

    __shared__ float hs[D_];
    ((float4*)hs)[tid] = hv4;
    __syncthreads();

    const float* __restrict__ hp = hs + ig * ILEN;

    float acc = 0.f;
#pragma unroll
    for (int p = 0; p < PF; ++p) acc += hp[p] * pf[p];
#pragma unroll 32
    for (int i = PF; i < ILEN; ++i)
        acc += hp[i] * __builtin_nontemporal_load(&Wp[(size_t)i * D_]);

    __shared__ float red[IG][JT];
    red[ig][jl] = acc;
    __syncthreads();

    if (tid < JT) {
        float s = bsv;
#pragma unroll
        for (int g = 0; g < IG; ++g) s += red[g][tid];
        if (mv) s = fmaxf(s, 0.f);
        hout[t] = s;
    }
}

extern "C" void kernel_launch(void* const* d_in, const int* in_sizes, int n_in,
                              void* d_out, int out_size, void* d_ws, size_t ws_size,
                              hipStream_t stream) {
    const float* x  = (const float*)d_in[0];
    const float* W  = (const float*)d_in[1];
    const float* Bs = (const float*)d_in[2];
    const int*   M  = (const int*)d_in[3];

    float* hA = (float*)d_ws;
    float* hB = hA + (size_t)B_ * D_;

    const float* hin = x;
    for (int l = 0; l < L_; ++l) {
        float* hout = (l == L_ - 1) ? (float*)d_out : ((l & 1) ? hB : hA);
        layer_full<<<B_ * (D_ / JT), 256, 0, stream>>>(
            hin,
            W  + (size_t)l * B_ * D_ * D_,
            Bs + (size_t)l * B_ * D_,
            M  + (size_t)l * B_ * D_,
            hout);
        hin = hout;
    }
}

// Round 9
// 109.283 us; speedup vs baseline: 1.0314x; 1.0314x over previous
//
#include <hip/hip_runtime.h>

#define L_ 8
#define B_ 16
#define D_ 1024
#define JT 32              // output-column tile per block
#define IG 8               // i-groups per block (tid >> 5)
#define ILEN (D_ / IG)     // 128 reduction rows per i-group
#define PF 32              // W rows prefetched before the h stage (PF=64 regressed)

// One block computes out[b, jt*JT : (jt+1)*JT] with the FULL i-reduction.
// Grid: B_ * (D_/JT) = 512 blocks, 256 threads (2 blocks/CU).
__global__ __launch_bounds__(256) void layer_full(
    const float* __restrict__ h,     // [B][D] input activations
    const float* __restrict__ W,     // layer base [B][D][D]
    const float* __restrict__ bias,  // layer base [B][D]
    const int*   __restrict__ mask,  // layer base [B][D]
    float* __restrict__ hout)        // [B][D]
{
    const int blk = blockIdx.x;
    const int b   = blk / (D_ / JT);
    const int jt  = blk % (D_ / JT);
    const int tid = threadIdx.x;
    const int jl  = tid & 31;        // lane within j-tile
    const int ig  = tid >> 5;        // i-group 0..7

    // 1) Issue the dependent h load FIRST (it heads the vmcnt queue).
    const float4 hv4 = ((const float4*)(h + (size_t)b * D_))[tid];

    // 2) Then issue a 32-row W prefetch. Because h was issued first, the
    //    ds_write below only needs vmcnt(PF) — these stay in flight through
    //    the h stage and the barrier.
    const float* __restrict__ Wp =
        W + (size_t)b * D_ * D_ + (size_t)(ig * ILEN) * D_ + jt * JT + jl;
    float pf[PF];
#pragma unroll
    for (int p = 0; p < PF; ++p)
        pf[p] = __builtin_nontemporal_load(&Wp[(size_t)p * D_]);

    __shared__ float hs[D_];
    ((float4*)hs)[tid] = hv4;

    // Hoist the tiny epilogue loads (issued behind the prefetch, used last).
    float bsv = 0.f;
    int   mv  = 0;
    const int t = b * D_ + jt * JT + (tid & 31);
    if (tid < JT) { bsv = bias[t]; mv = mask[t]; }

    __syncthreads();

    const float* __restrict__ hp = hs + ig * ILEN;

    float acc = 0.f;
#pragma unroll
    for (int p = 0; p < PF; ++p) acc += hp[p] * pf[p];
#pragma unroll 32
    for (int i = PF; i < ILEN; ++i)
        acc += hp[i] * __builtin_nontemporal_load(&Wp[(size_t)i * D_]);

    __shared__ float red[IG][JT];
    red[ig][jl] = acc;
    __syncthreads();

    if (tid < JT) {
        float s = bsv;
#pragma unroll
        for (int g = 0; g < IG; ++g) s += red[g][tid];
        if (mv) s = fmaxf(s, 0.f);
        hout[t] = s;
    }
}

extern "C" void kernel_launch(void* const* d_in, const int* in_sizes, int n_in,
                              void* d_out, int out_size, void* d_ws, size_t ws_size,
                              hipStream_t stream) {
    const float* x  = (const float*)d_in[0];
    const float* W  = (const float*)d_in[1];
    const float* Bs = (const float*)d_in[2];
    const int*   M  = (const int*)d_in[3];

    float* hA = (float*)d_ws;
    float* hB = hA + (size_t)B_ * D_;

    const float* hin = x;
    for (int l = 0; l < L_; ++l) {
        float* hout = (l == L_ - 1) ? (float*)d_out : ((l & 1) ? hB : hA);
        layer_full<<<B_ * (D_ / JT), 256, 0, stream>>>(
            hin,
            W  + (size_t)l * B_ * D_ * D_,
            Bs + (size_t)l * B_ * D_,
            M  + (size_t)l * B_ * D_,
            hout);
        hin = hout;
    }
}